// Round 10
// baseline (407.288 us; speedup 1.0000x reference)
//
#include <hip/hip_runtime.h>
#include <cstddef>
#include <cstdint>

#define NTOK 4096
#define NB_  8

typedef float f32x4  __attribute__((ext_vector_type(4)));
typedef float f32x16 __attribute__((ext_vector_type(16)));
typedef short s16x8  __attribute__((ext_vector_type(8)));

static __device__ __forceinline__ unsigned short f2bf(float f) {
    unsigned u = __float_as_uint(f);
    unsigned r = (u + 0x7FFFu + ((u >> 16) & 1u)) >> 16;
    return (unsigned short)r;
}
static __device__ __forceinline__ unsigned packbf2(float a, float b) {
    const unsigned ua = __float_as_uint(a) + 0x8000u;
    const unsigned ub = __float_as_uint(b) + 0x8000u;
    return __builtin_amdgcn_perm(ub, ua, 0x07060302u);  // [bf16(a), bf16(b)]
}

// ---------------- P0: weights fp32 -> bf16 ----------------
__global__ __launch_bounds__(256) void wcvt_kernel(
    const float* __restrict__ Wq, const float* __restrict__ Wk, const float* __restrict__ Wv,
    unsigned short* __restrict__ wvb, unsigned short* __restrict__ wqb,
    unsigned short* __restrict__ wkb)
{
    int i = blockIdx.x * 256 + threadIdx.x;  // 0..20479
    if (i < 16384)      wvb[i]         = f2bf(Wv[i]);
    else if (i < 18432) wqb[i - 16384] = f2bf(Wq[i - 16384]);
    else                wkb[i - 18432] = f2bf(Wk[i - 18432]);
}

// ---------------- P1: fused transpose + projections ----------------
// Flat grid 512 blocks; b = blk & 7 pins each batch to one XCD so outputs land
// in the L2 flash will read. V is written in flash's fragment-major layout:
// v3[b][jt=j>>6][s=(j>>4)&3][h=(j>>3)&1][c][e=j&7]
__global__ __launch_bounds__(256) void proj_kernel(
    const float* __restrict__ x,
    const unsigned short* __restrict__ wvb, const unsigned short* __restrict__ wqb,
    const unsigned short* __restrict__ wkb,
    const float* __restrict__ bq, const float* __restrict__ bk, const float* __restrict__ bv,
    unsigned short* __restrict__ qb, unsigned short* __restrict__ kb,
    unsigned short* __restrict__ vt)
{
    __shared__ float lt[128][68];   // [c][n0..63], padded rows
    const int t = threadIdx.x;
    const int w = t >> 6, lane = t & 63;
    const int c16 = lane & 15, g16 = lane >> 4;
    const int b  = blockIdx.x & 7;
    const int n0 = (blockIdx.x >> 3) * 64;

    // stage x tile: 128 rows x 64 floats
    {
        const int n4 = t & 15;
#pragma unroll
        for (int pass = 0; pass < 8; ++pass) {
            const int c = (t >> 4) + 16 * pass;
            const float4 val = ((const float4*)(x + ((size_t)b * 128 + c) * NTOK + n0))[n4];
            *(float4*)&lt[c][n4 * 4] = val;
        }
    }
    __syncthreads();

    // xf fragments for this wave's 16 tokens (token = n0 + 16w + c16)
    const int nl = 16 * w + c16;
    s16x8 xf[4];
#pragma unroll
    for (int kc = 0; kc < 4; ++kc) {
        unsigned rr[8];
#pragma unroll
        for (int i = 0; i < 8; ++i) {
            const unsigned u = __float_as_uint(lt[32 * kc + 8 * g16 + i][nl]);
            rr[i] = u + 0x7FFFu + ((u >> 16) & 1u);
        }
        union { s16x8 v; unsigned u[4]; } cvt;
#pragma unroll
        for (int d = 0; d < 4; ++d)
            cvt.u[d] = __builtin_amdgcn_perm(rr[2 * d + 1], rr[2 * d], 0x07060302u);
        xf[kc] = cvt.v;
    }

    // ---- V = Wv * X  (stored fragment-major for flash) ----
    // token j = n0 + 16w + c16: jt = n0>>6, s = w, h = c16>>3, e = c16&7
    unsigned short* vwp = vt + (size_t)b * (NTOK * 128) +
                          (size_t)(((n0 >> 6) * 8) + 2 * w + (c16 >> 3)) * 1024 + (c16 & 7);
#pragma unroll
    for (int mt = 0; mt < 8; ++mt) {
        f32x4 acc = {0.f, 0.f, 0.f, 0.f};
#pragma unroll
        for (int kc = 0; kc < 4; ++kc) {
            const s16x8 wf = *(const s16x8*)(wvb + (size_t)(16 * mt + c16) * 128 + 32 * kc + 8 * g16);
            acc = __builtin_amdgcn_mfma_f32_16x16x32_bf16(wf, xf[kc], acc, 0, 0, 0);
        }
        const float4 bvv = *(const float4*)(bv + 16 * mt + 4 * g16);
#pragma unroll
        for (int r = 0; r < 4; ++r) {
            const int c = 16 * mt + 4 * g16 + r;
            vwp[c * 8] = f2bf(acc[r] + ((const float*)&bvv)[r]);
        }
    }
    // ---- Q, K ----
    f32x4 aq = {0.f, 0.f, 0.f, 0.f}, ak = {0.f, 0.f, 0.f, 0.f};
#pragma unroll
    for (int kc = 0; kc < 4; ++kc) {
        const s16x8 wqf = *(const s16x8*)(wqb + (size_t)c16 * 128 + 32 * kc + 8 * g16);
        const s16x8 wkf = *(const s16x8*)(wkb + (size_t)c16 * 128 + 32 * kc + 8 * g16);
        aq = __builtin_amdgcn_mfma_f32_16x16x32_bf16(xf[kc], wqf, aq, 0, 0, 0);
        ak = __builtin_amdgcn_mfma_f32_16x16x32_bf16(xf[kc], wkf, ak, 0, 0, 0);
    }
    const float bqv = bq[c16], bkv = bk[c16];
#pragma unroll
    for (int r = 0; r < 4; ++r) {
        const int n = n0 + 16 * w + 4 * g16 + r;
        qb[((size_t)b * NTOK + n) * 16 + c16] = f2bf(0.25f * (aq[r] + bqv));
        kb[((size_t)b * NTOK + n) * 16 + c16] = f2bf(ak[r] + bkv);
    }
}

// ---------------- P2: flash attention, c-split waves ----------------
// Flat grid 1024 blocks: b = blk & 7 (one batch per XCD), m-tile = blk >> 3 (32 q rows).
// Wave w owns c-quarter [32w, 32w+32) and iterates ALL 4096 j (64 tiles).
// Scores/softmax redundant per wave; NO LDS, NO __syncthreads, no combine.
// Register budget pinned via amdgpu_waves_per_eu(4,4): 512/4 = 128 regs —
// above the ~105 needed, and max=4 stops the backend's occupancy heuristic
// from squeezing to 64 regs + scratch spill (R9: VGPR=64, 260 MB WRITE_SIZE).
// 4 blocks/CU resident = entire 1024-block grid in one pass, zero tail.
__global__ __launch_bounds__(256)
__attribute__((amdgpu_waves_per_eu(4, 4)))
void flash_kernel(
    const unsigned short* __restrict__ qb, const unsigned short* __restrict__ kb,
    const unsigned short* __restrict__ vt, const float* __restrict__ x,
    const float* __restrict__ gamma, float* __restrict__ out)
{
    const int t = threadIdx.x;
    const int w = t >> 6, lane = t & 63;
    const int m31 = lane & 31, h = lane >> 5;
    const int b  = blockIdx.x & 7;
    const int m0 = (blockIdx.x >> 3) * 32;

    const unsigned short* kbb = kb + (size_t)b * NTOK * 16;
    // fragment-major V base: this wave's c-quarter (ct = w)
    const unsigned short* vtb = vt + (size_t)b * (NTOK * 128) + w * 256 +
                                h * 1024 + m31 * 8;

    // Q B-frag: B[k=ch 8h+e][n=m31]; scale pre-folded into qb.
    const s16x8 qf = *(const s16x8*)(qb + ((size_t)b * NTOK + m0 + m31) * 16 + 8 * h);

    f32x16 O;
#pragma unroll
    for (int r = 0; r < 16; ++r) O[r] = 0.f;
    float l_acc = 0.f;

    // K A-frags for jt=0
    s16x8 kf0 = *(const s16x8*)(kbb + (size_t)m31 * 16 + 8 * h);
    s16x8 kf1 = *(const s16x8*)(kbb + (size_t)(32 + m31) * 16 + 8 * h);

    const int xaddr = (lane ^ 32) << 2;   // bpermute byte-address of h-partner

    for (int jt = 0; jt < 64; ++jt) {
        const int j0 = jt * 64;

        // V A-frags for own c-quarter, coalesced (two 512B segments per load)
        s16x8 vf[4];
#pragma unroll
        for (int s = 0; s < 4; ++s)
            vf[s] = *(const s16x8*)(vtb + jt * 8192 + s * 2048);

        // scores: S^T tiles (D[j][m])
        f32x16 sd[2];
#pragma unroll
        for (int r = 0; r < 16; ++r) { sd[0][r] = 0.f; sd[1][r] = 0.f; }
        sd[0] = __builtin_amdgcn_mfma_f32_32x32x16_bf16(kf0, qf, sd[0], 0, 0, 0);
        sd[1] = __builtin_amdgcn_mfma_f32_32x32x16_bf16(kf1, qf, sd[1], 0, 0, 0);

        // prefetch next K frags
        if (jt < 63) {
            kf0 = *(const s16x8*)(kbb + (size_t)(j0 + 64 + m31) * 16 + 8 * h);
            kf1 = *(const s16x8*)(kbb + (size_t)(j0 + 96 + m31) * 16 + 8 * h);
        }

        // softmax without max-subtraction (|s| bounded; exp safe in fp32)
#pragma unroll
        for (int t2 = 0; t2 < 2; ++t2)
#pragma unroll
            for (int r = 0; r < 16; ++r) {
                const float e = __expf(sd[t2][r]);
                sd[t2][r] = e;
                l_acc += e;
            }

        // pack C/D quads to bf16 dword-pairs
        uint2 pk[2][4];
#pragma unroll
        for (int t2 = 0; t2 < 2; ++t2)
#pragma unroll
            for (int q = 0; q < 4; ++q) {
                pk[t2][q].x = packbf2(sd[t2][4 * q + 0], sd[t2][4 * q + 1]);
                pk[t2][q].y = packbf2(sd[t2][4 * q + 2], sd[t2][4 * q + 3]);
            }

        // register-only C->B transform: exchange with h-partner (lane^32)
        uint2 ex[2][2];
#pragma unroll
        for (int t2 = 0; t2 < 2; ++t2)
#pragma unroll
            for (int s1 = 0; s1 < 2; ++s1) {
                const uint2 snd = h ? pk[t2][2 * s1] : pk[t2][2 * s1 + 1];
                ex[t2][s1].x = (unsigned)__builtin_amdgcn_ds_bpermute(xaddr, (int)snd.x);
                ex[t2][s1].y = (unsigned)__builtin_amdgcn_ds_bpermute(xaddr, (int)snd.y);
            }

        // assemble pf[s]: B[k=8h+e][n=m31] = P^T[j=16s+8h+e][m31]
        s16x8 pf[4];
#pragma unroll
        for (int s = 0; s < 4; ++s) {
            const int t2 = s >> 1, s1 = s & 1;
            const uint2 lo = h ? ex[t2][s1] : pk[t2][2 * s1];
            const uint2 hi = h ? pk[t2][2 * s1 + 1] : ex[t2][s1];
            union { s16x8 v; unsigned u[4]; } asm_;
            asm_.u[0] = lo.x; asm_.u[1] = lo.y; asm_.u[2] = hi.x; asm_.u[3] = hi.y;
            pf[s] = asm_.v;
        }

        // PV: O^T[c][m] += V^T * P^T  (own c-quarter only)
#pragma unroll
        for (int s = 0; s < 4; ++s)
            O = __builtin_amdgcn_mfma_f32_32x32x16_bf16(vf[s], pf[s], O, 0, 0, 0);
    }

    // l: two h-halves hold disjoint j subsets of the same m-row
    l_acc += __shfl_xor(l_acc, 32);

    // epilogue: each wave writes its own c-quarter; no cross-wave combine
    const float linv = 1.f / l_acc;
    const float g = gamma[0];
#pragma unroll
    for (int r = 0; r < 16; ++r) {
        const int c = 32 * w + (r & 3) + 8 * (r >> 2) + 4 * h;
        const size_t idx = ((size_t)b * 128 + c) * NTOK + m0 + m31;
        out[idx] = fmaf(g, O[r] * linv, x[idx]);
    }
}

extern "C" void kernel_launch(void* const* d_in, const int* in_sizes, int n_in,
                              void* d_out, int out_size, void* d_ws, size_t ws_size,
                              hipStream_t stream)
{
    const float* x     = (const float*)d_in[0];
    const float* Wq    = (const float*)d_in[1];
    const float* bq    = (const float*)d_in[2];
    const float* Wk    = (const float*)d_in[3];
    const float* bk    = (const float*)d_in[4];
    const float* Wv    = (const float*)d_in[5];
    const float* bv    = (const float*)d_in[6];
    const float* gamma = (const float*)d_in[7];
    float* out = (float*)d_out;

    // workspace (bf16 elements)
    unsigned short* qb  = (unsigned short*)d_ws;                 // 8*4096*16
    unsigned short* kb  = qb  + (size_t)NB_ * NTOK * 16;
    unsigned short* vt  = kb  + (size_t)NB_ * NTOK * 16;         // 8*128*4096 (fragment-major)
    unsigned short* wvb = vt  + (size_t)NB_ * 128 * NTOK;        // 128*128
    unsigned short* wqb = wvb + 16384;                           // 16*128
    unsigned short* wkb = wqb + 2048;

    wcvt_kernel<<<80, 256, 0, stream>>>(Wq, Wk, Wv, wvb, wqb, wkb);
    proj_kernel<<<512, 256, 0, stream>>>(x, wvb, wqb, wkb, bq, bk, bv, qb, kb, vt);
    flash_kernel<<<1024, 256, 0, stream>>>(qb, kb, vt, x, gamma, out);
}

// Round 11
// 264.028 us; speedup vs baseline: 1.5426x; 1.5426x over previous
//
#include <hip/hip_runtime.h>
#include <cstddef>
#include <cstdint>

#define NTOK 4096
#define NB_  8

typedef float f32x4  __attribute__((ext_vector_type(4)));
typedef float f32x16 __attribute__((ext_vector_type(16)));
typedef short s16x8  __attribute__((ext_vector_type(8)));

static __device__ __forceinline__ unsigned short f2bf(float f) {
    unsigned u = __float_as_uint(f);
    unsigned r = (u + 0x7FFFu + ((u >> 16) & 1u)) >> 16;
    return (unsigned short)r;
}
static __device__ __forceinline__ unsigned packbf2(float a, float b) {
    const unsigned ua = __float_as_uint(a) + 0x8000u;
    const unsigned ub = __float_as_uint(b) + 0x8000u;
    return __builtin_amdgcn_perm(ub, ua, 0x07060302u);  // [bf16(a), bf16(b)]
}

// async global->LDS copy, 16 B per lane; LDS dest = uniform base + lane*16
#define GLD16(gsrc, ldst) __builtin_amdgcn_global_load_lds( \
    (const __attribute__((address_space(1))) unsigned int*)(gsrc), \
    (__attribute__((address_space(3))) unsigned int*)(ldst), 16, 0, 0)

// ---------------- P0: weights fp32 -> bf16 ----------------
__global__ __launch_bounds__(256) void wcvt_kernel(
    const float* __restrict__ Wq, const float* __restrict__ Wk, const float* __restrict__ Wv,
    unsigned short* __restrict__ wvb, unsigned short* __restrict__ wqb,
    unsigned short* __restrict__ wkb)
{
    int i = blockIdx.x * 256 + threadIdx.x;  // 0..20479
    if (i < 16384)      wvb[i]         = f2bf(Wv[i]);
    else if (i < 18432) wqb[i - 16384] = f2bf(Wq[i - 16384]);
    else                wkb[i - 18432] = f2bf(Wk[i - 18432]);
}

// ---------------- P1: fused transpose + projections ----------------
// Flat grid 512 blocks; b = blk & 7 pins each batch to one XCD so outputs land
// in the L2 flash will read. V is written in flash's fragment-major layout:
// v3[b][jt=j>>6][s=(j>>4)&3][h=(j>>3)&1][c][e=j&7]  (each jt tile = 16 KB contiguous)
__global__ __launch_bounds__(256) void proj_kernel(
    const float* __restrict__ x,
    const unsigned short* __restrict__ wvb, const unsigned short* __restrict__ wqb,
    const unsigned short* __restrict__ wkb,
    const float* __restrict__ bq, const float* __restrict__ bk, const float* __restrict__ bv,
    unsigned short* __restrict__ qb, unsigned short* __restrict__ kb,
    unsigned short* __restrict__ vt)
{
    __shared__ float lt[128][68];   // [c][n0..63], padded rows
    const int t = threadIdx.x;
    const int w = t >> 6, lane = t & 63;
    const int c16 = lane & 15, g16 = lane >> 4;
    const int b  = blockIdx.x & 7;
    const int n0 = (blockIdx.x >> 3) * 64;

    // stage x tile: 128 rows x 64 floats
    {
        const int n4 = t & 15;
#pragma unroll
        for (int pass = 0; pass < 8; ++pass) {
            const int c = (t >> 4) + 16 * pass;
            const float4 val = ((const float4*)(x + ((size_t)b * 128 + c) * NTOK + n0))[n4];
            *(float4*)&lt[c][n4 * 4] = val;
        }
    }
    __syncthreads();

    // xf fragments for this wave's 16 tokens (token = n0 + 16w + c16)
    const int nl = 16 * w + c16;
    s16x8 xf[4];
#pragma unroll
    for (int kc = 0; kc < 4; ++kc) {
        unsigned rr[8];
#pragma unroll
        for (int i = 0; i < 8; ++i) {
            const unsigned u = __float_as_uint(lt[32 * kc + 8 * g16 + i][nl]);
            rr[i] = u + 0x7FFFu + ((u >> 16) & 1u);
        }
        union { s16x8 v; unsigned u[4]; } cvt;
#pragma unroll
        for (int d = 0; d < 4; ++d)
            cvt.u[d] = __builtin_amdgcn_perm(rr[2 * d + 1], rr[2 * d], 0x07060302u);
        xf[kc] = cvt.v;
    }

    // ---- V = Wv * X  (stored fragment-major for flash) ----
    // token j = n0 + 16w + c16: jt = n0>>6, s = w, h = c16>>3, e = c16&7
    unsigned short* vwp = vt + (size_t)b * (NTOK * 128) +
                          (size_t)(((n0 >> 6) * 8) + 2 * w + (c16 >> 3)) * 1024 + (c16 & 7);
#pragma unroll
    for (int mt = 0; mt < 8; ++mt) {
        f32x4 acc = {0.f, 0.f, 0.f, 0.f};
#pragma unroll
        for (int kc = 0; kc < 4; ++kc) {
            const s16x8 wf = *(const s16x8*)(wvb + (size_t)(16 * mt + c16) * 128 + 32 * kc + 8 * g16);
            acc = __builtin_amdgcn_mfma_f32_16x16x32_bf16(wf, xf[kc], acc, 0, 0, 0);
        }
        const float4 bvv = *(const float4*)(bv + 16 * mt + 4 * g16);
#pragma unroll
        for (int r = 0; r < 4; ++r) {
            const int c = 16 * mt + 4 * g16 + r;
            vwp[c * 8] = f2bf(acc[r] + ((const float*)&bvv)[r]);
        }
    }
    // ---- Q, K ----
    f32x4 aq = {0.f, 0.f, 0.f, 0.f}, ak = {0.f, 0.f, 0.f, 0.f};
#pragma unroll
    for (int kc = 0; kc < 4; ++kc) {
        const s16x8 wqf = *(const s16x8*)(wqb + (size_t)c16 * 128 + 32 * kc + 8 * g16);
        const s16x8 wkf = *(const s16x8*)(wkb + (size_t)c16 * 128 + 32 * kc + 8 * g16);
        aq = __builtin_amdgcn_mfma_f32_16x16x32_bf16(xf[kc], wqf, aq, 0, 0, 0);
        ak = __builtin_amdgcn_mfma_f32_16x16x32_bf16(xf[kc], wkf, ak, 0, 0, 0);
    }
    const float bqv = bq[c16], bkv = bk[c16];
#pragma unroll
    for (int r = 0; r < 4; ++r) {
        const int n = n0 + 16 * w + 4 * g16 + r;
        qb[((size_t)b * NTOK + n) * 16 + c16] = f2bf(0.25f * (aq[r] + bqv));
        kb[((size_t)b * NTOK + n) * 16 + c16] = f2bf(ak[r] + bkv);
    }
}

// ---------------- P2: flash attention, LDS-staged double-buffered V/K ----------------
// Flat grid 512 blocks (2/CU): b = blk & 7 (one batch per XCD), M=64 q rows per block.
// Wave w = (mw = w&1, cw = w>>1): m-tile m0+32*mw, c-half 64*cw. Each wave does ALL j.
// V tile (16 KB, contiguous in fragment-major vt) + K tile (2 KB) staged via
// global_load_lds width=16, double-buffered: stage(jt+1) issues right after the
// barrier, completes during compute(jt) -> V latency off the dependency chain.
// O = 2 x f32x16 (32 acc regs) per wave; no cross-wave combine (disjoint m,c).
// launch_bounds (256,2): known-safe floor. [c-split R9/R10: compiler forced
// 64-VGPR + 260-320 MB scratch spill regardless of waves_per_eu — abandoned.]
__global__ __launch_bounds__(256, 2) void flash_kernel(
    const unsigned short* __restrict__ qb, const unsigned short* __restrict__ kb,
    const unsigned short* __restrict__ vt, const float* __restrict__ x,
    const float* __restrict__ gamma, float* __restrict__ out)
{
    __shared__ __align__(16) unsigned short vbuf[2][8192];  // 2 x 16 KB
    __shared__ __align__(16) unsigned short kbuf[2][1024];  // 2 x 2 KB

    const int t = threadIdx.x;
    const int w = t >> 6, lane = t & 63;
    const int m31 = lane & 31, h = lane >> 5;
    const int mw = w & 1, cw = w >> 1;
    const int b  = blockIdx.x & 7;
    const int m0 = (blockIdx.x >> 3) * 64;

    const char* vtb = (const char*)(vt + (size_t)b * (NTOK * 128));  // tile jt at +jt*16384 B
    const char* kbb = (const char*)(kb + (size_t)b * NTOK * 16);     // tile jt at +jt*2048 B

    // Q B-frag for this wave's 32 q rows; scale pre-folded into qb.
    const s16x8 qf = *(const s16x8*)(qb + ((size_t)b * NTOK + m0 + 32 * mw + m31) * 16 + 8 * h);

    f32x16 O0, O1;
#pragma unroll
    for (int r = 0; r < 16; ++r) { O0[r] = 0.f; O1[r] = 0.f; }
    float l_acc = 0.f;
    const int xaddr = (lane ^ 32) << 2;   // bpermute byte-address of h-partner

    // ---- stage tile 0 ----
    {
        const char* vsrc = vtb;
        char* vdst = (char*)vbuf[0];
#pragma unroll
        for (int i = 0; i < 4; ++i) {
            const int off = i * 4096 + w * 1024;
            GLD16(vsrc + off + lane * 16, vdst + off);
        }
        if (w < 2) GLD16(kbb + w * 1024 + lane * 16, (char*)kbuf[0] + w * 1024);
    }

    for (int jt = 0; jt < 64; ++jt) {
        __syncthreads();   // compiler drains vmcnt -> buf[jt&1] staged & prev reads done

        if (jt < 63) {     // stage next tile into other buffer (overlaps compute below)
            const char* vsrc = vtb + (size_t)(jt + 1) * 16384;
            char* vdst = (char*)vbuf[(jt + 1) & 1];
#pragma unroll
            for (int i = 0; i < 4; ++i) {
                const int off = i * 4096 + w * 1024;
                GLD16(vsrc + off + lane * 16, vdst + off);
            }
            if (w < 2) GLD16(kbb + (size_t)(jt + 1) * 2048 + w * 1024 + lane * 16,
                             (char*)kbuf[(jt + 1) & 1] + w * 1024);
        }

        const char* vb = (const char*)vbuf[jt & 1];
        const char* kp = (const char*)kbuf[jt & 1];

        // K A-frags from LDS: A[m=j_local][k=ch]
        const s16x8 kf0 = *(const s16x8*)(kp + m31 * 32 + h * 16);
        const s16x8 kf1 = *(const s16x8*)(kp + 1024 + m31 * 32 + h * 16);

        // scores: S^T tiles (D[j][m])
        f32x16 sd[2];
#pragma unroll
        for (int r = 0; r < 16; ++r) { sd[0][r] = 0.f; sd[1][r] = 0.f; }
        sd[0] = __builtin_amdgcn_mfma_f32_32x32x16_bf16(kf0, qf, sd[0], 0, 0, 0);
        sd[1] = __builtin_amdgcn_mfma_f32_32x32x16_bf16(kf1, qf, sd[1], 0, 0, 0);

        // softmax without max-subtraction (|s| bounded; exp safe in fp32)
#pragma unroll
        for (int t2 = 0; t2 < 2; ++t2)
#pragma unroll
            for (int r = 0; r < 16; ++r) {
                const float e = __expf(sd[t2][r]);
                sd[t2][r] = e;
                l_acc += e;
            }

        // pack C/D quads to bf16 dword-pairs
        uint2 pk[2][4];
#pragma unroll
        for (int t2 = 0; t2 < 2; ++t2)
#pragma unroll
            for (int q = 0; q < 4; ++q) {
                pk[t2][q].x = packbf2(sd[t2][4 * q + 0], sd[t2][4 * q + 1]);
                pk[t2][q].y = packbf2(sd[t2][4 * q + 2], sd[t2][4 * q + 3]);
            }

        // register-only C->B transform: exchange with h-partner (lane^32)
        uint2 ex[2][2];
#pragma unroll
        for (int t2 = 0; t2 < 2; ++t2)
#pragma unroll
            for (int s1 = 0; s1 < 2; ++s1) {
                const uint2 snd = h ? pk[t2][2 * s1] : pk[t2][2 * s1 + 1];
                ex[t2][s1].x = (unsigned)__builtin_amdgcn_ds_bpermute(xaddr, (int)snd.x);
                ex[t2][s1].y = (unsigned)__builtin_amdgcn_ds_bpermute(xaddr, (int)snd.y);
            }

        // assemble pf[s]: B[k=8h+e][n=m31] = P^T[j=16s+8h+e][m31]
        s16x8 pf[4];
#pragma unroll
        for (int s = 0; s < 4; ++s) {
            const int t2 = s >> 1, s1 = s & 1;
            const uint2 lo = h ? ex[t2][s1] : pk[t2][2 * s1];
            const uint2 hi = h ? pk[t2][2 * s1 + 1] : ex[t2][s1];
            union { s16x8 v; unsigned u[4]; } asm_;
            asm_.u[0] = lo.x; asm_.u[1] = lo.y; asm_.u[2] = hi.x; asm_.u[3] = hi.y;
            pf[s] = asm_.v;
        }

        // PV from LDS: O^T[c][m] += V^T * P^T  (this wave's c-half = 2 ct tiles)
#pragma unroll
        for (int s = 0; s < 4; ++s) {
            const s16x8 vfa = *(const s16x8*)(vb + s * 4096 + h * 2048 + (64 * cw + m31) * 16);
            const s16x8 vfb = *(const s16x8*)(vb + s * 4096 + h * 2048 + (64 * cw + 32 + m31) * 16);
            O0 = __builtin_amdgcn_mfma_f32_32x32x16_bf16(vfa, pf[s], O0, 0, 0, 0);
            O1 = __builtin_amdgcn_mfma_f32_32x32x16_bf16(vfb, pf[s], O1, 0, 0, 0);
        }
    }

    // l: two h-halves hold disjoint j subsets of the same m-row
    l_acc += __shfl_xor(l_acc, 32);

    // epilogue: each wave writes its own (m-tile, c-half); no combine needed
    const float linv = 1.f / l_acc;
    const float g = gamma[0];
#pragma unroll
    for (int r = 0; r < 16; ++r) {
        const int cbase = 64 * cw + (r & 3) + 8 * (r >> 2) + 4 * h;
        const int m = m0 + 32 * mw + m31;
        const size_t i0 = ((size_t)b * 128 + cbase) * NTOK + m;
        const size_t i1 = ((size_t)b * 128 + cbase + 32) * NTOK + m;
        out[i0] = fmaf(g, O0[r] * linv, x[i0]);
        out[i1] = fmaf(g, O1[r] * linv, x[i1]);
    }
}

extern "C" void kernel_launch(void* const* d_in, const int* in_sizes, int n_in,
                              void* d_out, int out_size, void* d_ws, size_t ws_size,
                              hipStream_t stream)
{
    const float* x     = (const float*)d_in[0];
    const float* Wq    = (const float*)d_in[1];
    const float* bq    = (const float*)d_in[2];
    const float* Wk    = (const float*)d_in[3];
    const float* bk    = (const float*)d_in[4];
    const float* Wv    = (const float*)d_in[5];
    const float* bv    = (const float*)d_in[6];
    const float* gamma = (const float*)d_in[7];
    float* out = (float*)d_out;

    // workspace (bf16 elements)
    unsigned short* qb  = (unsigned short*)d_ws;                 // 8*4096*16
    unsigned short* kb  = qb  + (size_t)NB_ * NTOK * 16;
    unsigned short* vt  = kb  + (size_t)NB_ * NTOK * 16;         // 8*128*4096 (fragment-major)
    unsigned short* wvb = vt  + (size_t)NB_ * 128 * NTOK;        // 128*128
    unsigned short* wqb = wvb + 16384;                           // 16*128
    unsigned short* wkb = wqb + 2048;

    wcvt_kernel<<<80, 256, 0, stream>>>(Wq, Wk, Wv, wvb, wqb, wkb);
    proj_kernel<<<512, 256, 0, stream>>>(x, wvb, wqb, wkb, bq, bk, bv, qb, kb, vt);
    flash_kernel<<<512, 256, 0, stream>>>(qb, kb, vt, x, gamma, out);
}